// Round 9
// baseline (211.507 us; speedup 1.0000x reference)
//
#include <hip/hip_runtime.h>

// SpikingLayer forward: first-spike times of a delayed-synapse LIF layer.
// B=128, I=512+1 bias, O=512, STEPS=200.
// R8: R6/R7's 150us regression was launch_bounds(512,8) itself: the 64-VGPR
// budget it imposes flips the allocator into spill mode (~176MB scratch
// writes/dispatch, VGPR_Count 32) even though this kernel fits in ~40-56
// regs naturally (R2-era kernel: 40 regs under (512,6), zero spill).
// The 2nd launch_bounds arg is a request, not a prerequisite: if natural
// allocation lands <=64 regs, HW grants 8 waves/SIMD anyway. So: (512,6)
// budget, SPLIT=144 LDS diet kept (39.9KB -> 4 blocks/CU by LDS).
//  - depth-1 prefetch pipeline, pass B (rare tail) de-pipelined
//  - stride-65 charge rows: atomic bank = (s+col)%32
//  - numerics bit-identical to R5: exact bin via f64 mul (RNE == IEEE f32
//    div), deterministic fixed-point int binning, contract off.

#define IN_F    512
#define OUT_F   512
#define BATCH   128
#define STEPS   200
#define SPLIT   144                          // LDS-resident bins [0,SPLIT)
#define ROWS_B  (STEPS - SPLIT)              // 56 tail bins
#define RES_F   1e-4f
#define CSTRIDE 65                           // stride-65: bank=(s+col)%32
// double exp(-1e-4/5e-3) = exp(-0.02), rounded to f32 by the literal:
#define DECAY_F 0.98019867330675525f
// double (1.0 - exp(-0.02)), rounded to f32:
#define ONEMD_F 0.019801326693244747f
#define SIM_T_F 2e-2f
#define FPSCALE 8388608.0f                   // 2^23
#define INVSCALE 1.1920928955078125e-07f     // 2^-23, exact

// q = fl32(arr / 1e-4f) computed exactly: (double)arr*10000.0 is exact
// (24+14 sig bits <= 53), double->float cvt is RNE == IEEE f32 division.
__device__ __forceinline__ int bin_of(float arr) {
    float q = (float)((double)arr * 10000.0);
    int s = __float2int_rn(q);               // RNE == np.round half-to-even
    s = s < 0 ? 0 : (s > STEPS - 1 ? STEPS - 1 : s);
    return s;
}

__global__ __launch_bounds__(256) void prep_wi(
    const float* __restrict__ weights, int* __restrict__ wI)
{
    int idx = blockIdx.x * 256 + threadIdx.x;        // float4 index
    if (idx < (IN_F + 1) * OUT_F / 4) {
        float4 v = ((const float4*)weights)[idx];
        int4 r;
        r.x = __float2int_rn(v.x * FPSCALE);
        r.y = __float2int_rn(v.y * FPSCALE);
        r.z = __float2int_rn(v.z * FPSCALE);
        r.w = __float2int_rn(v.w * FPSCALE);
        ((int4*)wI)[idx] = r;
    }
}

__global__ __launch_bounds__(512, 6) void snn_fwd(
    const float* __restrict__ input_times,   // [B, IN_F]
    const int*   __restrict__ wI,            // [IN_F+1, OUT_F] fixed-point
    const float* __restrict__ delays,        // [IN_F+1, OUT_F]
    const float* __restrict__ thresholds,    // [OUT_F]
    float* __restrict__ out)                 // [B, OUT_F]
{
#pragma clang fp contract(off)
    __shared__ __align__(16) int chargeI[SPLIT * CSTRIDE];   // 37440 B
    __shared__ float times_s[IN_F];                          // 2048 B
    __shared__ int alldone_s;

    const int tid  = threadIdx.x;
    const int wv   = tid >> 6;               // wave 0..7
    const int lane = tid & 63;
    const int b     = blockIdx.x >> 3;
    const int otile = blockIdx.x & 7;
    const int ob    = otile << 6;            // output-column base

    // zero charge bins (int4) + stage this batch's input times
    {
        int4 z = make_int4(0, 0, 0, 0);
        int4* c4 = (int4*)chargeI;
        #pragma unroll
        for (int k = tid; k < (SPLIT * CSTRIDE) / 4; k += 512) c4[k] = z;
    }
    times_s[tid] = input_times[b * IN_F + tid];   // IN_F == blockDim == 512
    __syncthreads();

    // --- Phase 1A: bin synapse charges, steps [0, SPLIT) ---
    // lane -> (row-offset sub, column-group cg): one 16B load covers
    // 4 rows x 64 cols per wave. Wave wv handles rows [64*wv, 64*wv+64).
    const int sub = lane >> 4;               // 0..3
    const int cg  = (lane & 15) << 2;        // 0,4,...,60
    const int4*   __restrict__ Wp = (const int4*)wI;
    const float4* __restrict__ Dp = (const float4*)delays;
    const int r0   = wv << 6;                                // first row
    const int i0   = (r0 + sub) * (OUT_F / 4) + ((ob + cg) >> 2);
    const int gstr = 4 * (OUT_F / 4);                        // 4 rows of vec4s

    // bias row (i=512, spike time 0): wave 7, one column per lane
    if (wv == 7) {
        float dl = delays[IN_F * OUT_F + ob + lane];
        int   wt = wI[IN_F * OUT_F + ob + lane];
        int s = bin_of(dl);
        if (s < SPLIT) atomicAdd(&chargeI[s * CSTRIDE + lane], wt);
    }

    // depth-1 prefetch pipeline over 16 vec4-steps (low register pressure)
    {
        int4   wCur = Wp[i0];
        float4 dCur = Dp[i0];
        float  tCur = times_s[r0 + sub];
        #pragma unroll
        for (int g = 0; g < 16; ++g) {
            int4   wNxt = {};
            float4 dNxt = {};
            float  tNxt = 0.f;
            if (g < 15) {
                wNxt = Wp[i0 + (g + 1) * gstr];
                dNxt = Dp[i0 + (g + 1) * gstr];
                tNxt = times_s[r0 + ((g + 1) << 2) + sub];
            }
            const float* dv = (const float*)&dCur;
            const int*   wi = (const int*)&wCur;
            #pragma unroll
            for (int k = 0; k < 4; ++k) {
                int s = bin_of(tCur + dv[k]);
                if (s < SPLIT)
                    atomicAdd(&chargeI[s * CSTRIDE + cg + k], wi[k]);
            }
            wCur = wNxt; dCur = dNxt; tCur = tNxt;
        }
    }
    __syncthreads();

    // --- Phase 2A (wave 0): integrate steps 0..SPLIT-1 ---
    float syn = 0.f, mem = 0.f, spike_t = SIM_T_F, thr = 0.f;
    bool spiked = false;
    if (wv == 0) {
        thr = thresholds[ob + lane];
        for (int t0 = 0; t0 < SPLIT; t0 += 4) {
            float c[4];
            #pragma unroll
            for (int j = 0; j < 4; ++j)
                c[j] = (float)chargeI[(t0 + j) * CSTRIDE + lane] * INVSCALE;
            #pragma unroll
            for (int j = 0; j < 4; ++j) {
                float syn_n = syn * DECAY_F + c[j];               // no fma
                float mem_n = mem * DECAY_F + ONEMD_F * syn_n;    // no fma
                if (!spiked && mem_n >= thr) {
                    float denom = mem_n - mem;
                    float safe  = fabsf(denom) > 1e-12f ? denom : 1e-12f;
                    float frac  = (thr - mem) / safe;
                    frac = frac < 0.f ? 0.f : (frac > 1.f ? 1.f : frac);
                    spike_t = ((float)(t0 + j) + frac) * RES_F;
                    spiked  = true;
                }
                syn = syn_n; mem = mem_n;
            }
            if (__all(spiked)) break;        // => alldone, tail never needed
        }
        if (lane == 0) alldone_s = __all(spiked) ? 1 : 0;
    }
    __syncthreads();

    // --- Rare tail path: some lane unspiked at t=SPLIT ---
    if (!alldone_s) {
        {   // re-zero rows 0..ROWS_B-1 (reused for steps SPLIT..199)
            int4 z = make_int4(0, 0, 0, 0);
            int4* c4 = (int4*)chargeI;
            for (int k = tid; k < (ROWS_B * CSTRIDE) / 4; k += 512) c4[k] = z;
        }
        __syncthreads();
        if (wv == 7) {
            float dl = delays[IN_F * OUT_F + ob + lane];
            int   wt = wI[IN_F * OUT_F + ob + lane];
            int s = bin_of(dl);
            if (s >= SPLIT)
                atomicAdd(&chargeI[(s - SPLIT) * CSTRIDE + lane], wt);
        }
        // simple non-pipelined scan (rare path, keeps pressure low)
        for (int g = 0; g < 16; ++g) {
            int4   w4 = Wp[i0 + g * gstr];
            float4 d4 = Dp[i0 + g * gstr];
            float  tg = times_s[r0 + (g << 2) + sub];
            const float* dv = (const float*)&d4;
            const int*   wi = (const int*)&w4;
            #pragma unroll
            for (int k = 0; k < 4; ++k) {
                int s = bin_of(tg + dv[k]);
                if (s >= SPLIT)
                    atomicAdd(&chargeI[(s - SPLIT) * CSTRIDE + cg + k], wi[k]);
            }
        }
        __syncthreads();
        if (wv == 0) {
            // syn/mem are valid: alldone=0 implies no early break occurred
            for (int t0 = SPLIT; t0 < STEPS; t0 += 4) {
                float c[4];
                #pragma unroll
                for (int j = 0; j < 4; ++j)
                    c[j] = (float)chargeI[(t0 - SPLIT + j) * CSTRIDE + lane]
                           * INVSCALE;
                #pragma unroll
                for (int j = 0; j < 4; ++j) {
                    float syn_n = syn * DECAY_F + c[j];
                    float mem_n = mem * DECAY_F + ONEMD_F * syn_n;
                    if (!spiked && mem_n >= thr) {
                        float denom = mem_n - mem;
                        float safe  = fabsf(denom) > 1e-12f ? denom : 1e-12f;
                        float frac  = (thr - mem) / safe;
                        frac = frac < 0.f ? 0.f : (frac > 1.f ? 1.f : frac);
                        spike_t = ((float)(t0 + j) + frac) * RES_F;
                        spiked  = true;
                    }
                    syn = syn_n; mem = mem_n;
                }
                if (__all(spiked)) break;
            }
        }
    }
    if (wv == 0) out[b * OUT_F + ob + lane] = spike_t;
}

extern "C" void kernel_launch(void* const* d_in, const int* in_sizes, int n_in,
                              void* d_out, int out_size, void* d_ws, size_t ws_size,
                              hipStream_t stream) {
    const float* input_times = (const float*)d_in[0];   // [128, 512]
    const float* weights     = (const float*)d_in[1];   // [513, 512]
    const float* delays      = (const float*)d_in[2];   // [513, 512]
    const float* thresholds  = (const float*)d_in[3];   // [512]
    float* out = (float*)d_out;                         // [128, 512]
    int*   wI  = (int*)d_ws;                            // [513, 512] fixed-pt

    // prologue: weights -> fixed-point (runs every call; deterministic)
    int nvec4 = (IN_F + 1) * OUT_F / 4;                 // 65664
    prep_wi<<<(nvec4 + 255) / 256, 256, 0, stream>>>(weights, wI);

    dim3 grid(BATCH * (OUT_F / 64));   // 1024 blocks x 512 threads (8 waves)
    snn_fwd<<<grid, 512, 0, stream>>>(input_times, wI, delays, thresholds, out);
}

// Round 10
// 79.167 us; speedup vs baseline: 2.6716x; 2.6716x over previous
//
#include <hip/hip_runtime.h>

// SpikingLayer forward: first-spike times of a delayed-synapse LIF layer.
// B=128, I=512+1 bias, O=512, STEPS=200.
// R9: EXACT revert to the R5 kernel (best measured: bench 78.9us).
// R6/R7/R8 (time-SPLIT charge + tail pass) all regressed to 135-160us with
// ~140-176MB anomalous HBM writes regardless of pipeline depth or
// launch_bounds -> the SPLIT/tail structure itself triggers scratch demotion
// of the hot-loop vec4 locals (R8 disproved the pure VGPR-cap theory:
// VGPR=40, still leaking). This structure profiled clean (FETCH 2MB,
// WRITE 256KB, VGPR 40, no spill).
// Structure: full 200-row charge in LDS (52KB, 3 blocks/CU), 8 waves/block,
// depth-2 ping-pong vec4 loads, fixed-point ds_add_u32 binning
// (deterministic), exact sequential phase 2 on wave 0 with early exit.
// Numerics: bin via (float)((double)arr*10000.0) — f64 product exact
// (24+14<=53 bits), RNE cvt == IEEE f32 divide bit-for-bit; contract off.

#define IN_F    512
#define OUT_F   512
#define BATCH   128
#define STEPS   200
#define RES_F   1e-4f
#define CSTRIDE 65                           // stride-65: bank=(s+col)%32
// double exp(-1e-4/5e-3) = exp(-0.02), rounded to f32 by the literal:
#define DECAY_F 0.98019867330675525f
// double (1.0 - exp(-0.02)), rounded to f32:
#define ONEMD_F 0.019801326693244747f
#define SIM_T_F 2e-2f
#define FPSCALE 8388608.0f                   // 2^23
#define INVSCALE 1.1920928955078125e-07f     // 2^-23, exact

// q = fl32(arr / 1e-4f) computed exactly: (double)arr*10000.0 is exact,
// double->float is RNE == the IEEE f32 division result, bit for bit.
__device__ __forceinline__ int bin_of(float arr) {
    float q = (float)((double)arr * 10000.0);
    int s = __float2int_rn(q);               // RNE == np.round half-to-even
    s = s < 0 ? 0 : (s > STEPS - 1 ? STEPS - 1 : s);
    return s;
}

__global__ __launch_bounds__(256) void prep_wi(
    const float* __restrict__ weights, int* __restrict__ wI)
{
    int idx = blockIdx.x * 256 + threadIdx.x;        // float4 index
    if (idx < (IN_F + 1) * OUT_F / 4) {
        float4 v = ((const float4*)weights)[idx];
        int4 r;
        r.x = __float2int_rn(v.x * FPSCALE);
        r.y = __float2int_rn(v.y * FPSCALE);
        r.z = __float2int_rn(v.z * FPSCALE);
        r.w = __float2int_rn(v.w * FPSCALE);
        ((int4*)wI)[idx] = r;
    }
}

__global__ __launch_bounds__(512, 6) void snn_fwd(
    const float* __restrict__ input_times,   // [B, IN_F]
    const int*   __restrict__ wI,            // [IN_F+1, OUT_F] fixed-point
    const float* __restrict__ delays,        // [IN_F+1, OUT_F]
    const float* __restrict__ thresholds,    // [OUT_F]
    float* __restrict__ out)                 // [B, OUT_F]
{
#pragma clang fp contract(off)
    __shared__ __align__(16) int chargeI[STEPS * CSTRIDE];   // 52000 B
    __shared__ float times_s[IN_F];

    const int tid  = threadIdx.x;
    const int wv   = tid >> 6;               // wave 0..7
    const int lane = tid & 63;
    const int b     = blockIdx.x >> 3;
    const int otile = blockIdx.x & 7;
    const int ob    = otile << 6;            // output-column base

    // zero charge bins (int4) + stage this batch's input times
    {
        int4 z = make_int4(0, 0, 0, 0);
        int4* c4 = (int4*)chargeI;
        #pragma unroll
        for (int k = tid; k < (STEPS * CSTRIDE) / 4; k += 512) c4[k] = z;
    }
    times_s[tid] = input_times[b * IN_F + tid];   // IN_F == blockDim == 512
    __syncthreads();

    // --- Phase 1: bin synapse charges ---
    // lane -> (row-offset sub, column-group cg): one 16B load covers
    // 4 rows x 64 cols per wave. Wave wv handles rows [64*wv, 64*wv+64).
    const int sub = lane >> 4;               // 0..3
    const int cg  = (lane & 15) << 2;        // 0,4,...,60
    const int4*   __restrict__ Wp = (const int4*)wI;
    const float4* __restrict__ Dp = (const float4*)delays;
    const int r0   = wv << 6;                                // first row
    const int i0   = (r0 + sub) * (OUT_F / 4) + ((ob + cg) >> 2); // vec4 index
    const int gstr = 4 * (OUT_F / 4);                        // 4 rows of vec4s

    // bias row (i=512, spike time 0): wave 7, one column per lane
    if (wv == 7) {
        float dl = delays[IN_F * OUT_F + ob + lane];
        int   wt = wI[IN_F * OUT_F + ob + lane];
        atomicAdd(&chargeI[bin_of(dl) * CSTRIDE + lane], wt);
    }

    // static depth-2 ping-pong over 16 vec4-steps (fully unrolled)
    int4   wA = Wp[i0],            wB = Wp[i0 + gstr];
    float4 dA = Dp[i0],            dB = Dp[i0 + gstr];
    float  tA = times_s[r0 + sub];
    float  tB = times_s[r0 + 4 + sub];

    #pragma unroll
    for (int g = 0; g < 16; g += 2) {
        int4   wC = {}, wD = {};
        float4 dC = {}, dD = {};
        float  tC = 0.f, tD = 0.f;
        if (g + 2 < 16) {
            wC = Wp[i0 + (g + 2) * gstr]; dC = Dp[i0 + (g + 2) * gstr];
            tC = times_s[r0 + ((g + 2) << 2) + sub];
        }
        if (g + 3 < 16) {
            wD = Wp[i0 + (g + 3) * gstr]; dD = Dp[i0 + (g + 3) * gstr];
            tD = times_s[r0 + ((g + 3) << 2) + sub];
        }
        {   // consume step g
            const float* dv = (const float*)&dA;
            const int*   wi = (const int*)&wA;
            #pragma unroll
            for (int k = 0; k < 4; ++k) {
                int s = bin_of(tA + dv[k]);
                atomicAdd(&chargeI[s * CSTRIDE + cg + k], wi[k]);  // ds_add_u32
            }
        }
        {   // consume step g+1
            const float* dv = (const float*)&dB;
            const int*   wi = (const int*)&wB;
            #pragma unroll
            for (int k = 0; k < 4; ++k) {
                int s = bin_of(tB + dv[k]);
                atomicAdd(&chargeI[s * CSTRIDE + cg + k], wi[k]);
            }
        }
        wA = wC; dA = dC; tA = tC;
        wB = wD; dB = dD; tB = tD;
    }
    __syncthreads();

    // --- Phase 2 (wave 0 only): exact sequential leaky integration ---
    if (wv == 0) {
        const float thr = thresholds[ob + lane];
        float syn = 0.f, mem = 0.f, spike_t = SIM_T_F;
        bool spiked = false;
        for (int t0 = 0; t0 < STEPS; t0 += 4) {
            float c[4];
            #pragma unroll
            for (int j = 0; j < 4; ++j)               // batch the ds_reads
                c[j] = (float)chargeI[(t0 + j) * CSTRIDE + lane] * INVSCALE;
            #pragma unroll
            for (int j = 0; j < 4; ++j) {
                float syn_n = syn * DECAY_F + c[j];               // no fma
                float mem_n = mem * DECAY_F + ONEMD_F * syn_n;    // no fma
                if (!spiked && mem_n >= thr) {
                    float denom = mem_n - mem;
                    float safe  = fabsf(denom) > 1e-12f ? denom : 1e-12f;
                    float frac  = (thr - mem) / safe;
                    frac = frac < 0.f ? 0.f : (frac > 1.f ? 1.f : frac);
                    spike_t = ((float)(t0 + j) + frac) * RES_F;
                    spiked  = true;
                }
                syn = syn_n; mem = mem_n;
            }
            if (__all(spiked)) break;        // all 64 lanes latched
        }
        out[b * OUT_F + ob + lane] = spike_t;
    }
}

extern "C" void kernel_launch(void* const* d_in, const int* in_sizes, int n_in,
                              void* d_out, int out_size, void* d_ws, size_t ws_size,
                              hipStream_t stream) {
    const float* input_times = (const float*)d_in[0];   // [128, 512]
    const float* weights     = (const float*)d_in[1];   // [513, 512]
    const float* delays      = (const float*)d_in[2];   // [513, 512]
    const float* thresholds  = (const float*)d_in[3];   // [512]
    float* out = (float*)d_out;                         // [128, 512]
    int*   wI  = (int*)d_ws;                            // [513, 512] fixed-pt

    // prologue: weights -> fixed-point (runs every call; deterministic)
    int nvec4 = (IN_F + 1) * OUT_F / 4;                 // 65664
    prep_wi<<<(nvec4 + 255) / 256, 256, 0, stream>>>(weights, wI);

    dim3 grid(BATCH * (OUT_F / 64));   // 1024 blocks x 512 threads (8 waves)
    snn_fwd<<<grid, 512, 0, stream>>>(input_times, wI, delays, thresholds, out);
}